// Round 1
// baseline (769.333 us; speedup 1.0000x reference)
//
#include <hip/hip_runtime.h>

#define NN 50000
#define D 128
#define EPS 1e-8f

// ---------------- zero workspace (neigh + deg) ----------------
__global__ void zero_ws_kernel(float* __restrict__ p, int n_floats) {
    int i = (blockIdx.x * blockDim.x + threadIdx.x) * 4;
    if (i + 3 < n_floats) {
        *(float4*)(p + i) = make_float4(0.f, 0.f, 0.f, 0.f);
    } else {
        for (int k = i; k < n_floats; ++k) p[k] = 0.f;
    }
}

// ---------------- build WT_cat[256][128]: WT[k][j] = W_self[j][k] (k<128) else W_neigh[j][k-128]
__global__ void build_wt_kernel(const float* __restrict__ Ws,
                                const float* __restrict__ Wn,
                                float* __restrict__ WT) {
    int idx = blockIdx.x * 256 + threadIdx.x;   // 256*128 = 32768 total
    if (idx < 256 * 128) {
        int k = idx >> 7;
        int j = idx & 127;
        float v = (k < 128) ? Ws[j * 128 + k] : Wn[j * 128 + (k - 128)];
        WT[idx] = v;
    }
}

// ---------------- edge scatter: one wave (64 lanes) per edge ----------------
__global__ __launch_bounds__(256) void scatter_kernel(
        const float* __restrict__ x, const int* __restrict__ src,
        const int* __restrict__ dst, const float* __restrict__ ew,
        float* __restrict__ neigh, float* __restrict__ deg, int E) {
    int e = blockIdx.x * 4 + (threadIdx.x >> 6);
    if (e >= E) return;
    int lane = threadIdx.x & 63;
    int s = src[e];
    int d = dst[e];
    float w = ew[e];
    const float* xp = x + (size_t)s * D + lane * 2;
    float2 xv = *(const float2*)xp;
    float* np = neigh + (size_t)d * D + lane * 2;
    atomicAdd(np,     xv.x * w);
    atomicAdd(np + 1, xv.y * w);
    if (lane == 0) atomicAdd(deg + d, w);
}

// ---------------- fused normalize + dual GEMM + bias ----------------
// out[v][j] = b_self[j] + bias[j] + sum_k x[v][k]*Ws[j][k] + sum_k hn[v][k]*Wn[j][k]
// A-tile: 32 nodes x 256 (x concat hn) in LDS. Each thread: 4 nodes x 4 outputs.
__global__ __launch_bounds__(256) void fused_out_kernel(
        const float* __restrict__ x, const float* __restrict__ neigh,
        const float* __restrict__ deg, const float* __restrict__ WT,
        const float* __restrict__ b_self, const float* __restrict__ bias,
        float* __restrict__ out) {
    __shared__ float A[32][256];
    int tid = threadIdx.x;
    int v0 = blockIdx.x * 32;

    // stage x part: 32 nodes * 128 floats = 1024 float4
    for (int i = tid; i < 1024; i += 256) {
        int nn = i >> 5;
        int c4 = (i & 31) * 4;
        int v = v0 + nn;
        float4 val = make_float4(0.f, 0.f, 0.f, 0.f);
        if (v < NN) val = *(const float4*)(x + (size_t)v * D + c4);
        *(float4*)&A[nn][c4] = val;
    }
    // stage hn part: neigh / (deg+eps)
    for (int i = tid; i < 1024; i += 256) {
        int nn = i >> 5;
        int c4 = (i & 31) * 4;
        int v = v0 + nn;
        float4 val = make_float4(0.f, 0.f, 0.f, 0.f);
        if (v < NN) {
            val = *(const float4*)(neigh + (size_t)v * D + c4);
            float inv = 1.0f / (deg[v] + EPS);
            val.x *= inv; val.y *= inv; val.z *= inv; val.w *= inv;
        }
        *(float4*)&A[nn][128 + c4] = val;
    }
    __syncthreads();

    int j0 = (tid & 31) * 4;
    int ns = tid >> 5;   // 0..7 -> nodes ns*4 .. ns*4+3
    float acc[4][4];
    #pragma unroll
    for (int n = 0; n < 4; ++n)
        #pragma unroll
        for (int j = 0; j < 4; ++j) acc[n][j] = 0.f;

    for (int k4 = 0; k4 < 256; k4 += 4) {
        float4 w0 = *(const float4*)(WT + (k4 + 0) * D + j0);
        float4 w1 = *(const float4*)(WT + (k4 + 1) * D + j0);
        float4 w2 = *(const float4*)(WT + (k4 + 2) * D + j0);
        float4 w3 = *(const float4*)(WT + (k4 + 3) * D + j0);
        #pragma unroll
        for (int n = 0; n < 4; ++n) {
            float4 a = *(const float4*)&A[ns * 4 + n][k4];
            acc[n][0] = fmaf(a.x, w0.x, fmaf(a.y, w1.x, fmaf(a.z, w2.x, fmaf(a.w, w3.x, acc[n][0]))));
            acc[n][1] = fmaf(a.x, w0.y, fmaf(a.y, w1.y, fmaf(a.z, w2.y, fmaf(a.w, w3.y, acc[n][1]))));
            acc[n][2] = fmaf(a.x, w0.z, fmaf(a.y, w1.z, fmaf(a.z, w2.z, fmaf(a.w, w3.z, acc[n][2]))));
            acc[n][3] = fmaf(a.x, w0.w, fmaf(a.y, w1.w, fmaf(a.z, w2.w, fmaf(a.w, w3.w, acc[n][3]))));
        }
    }

    float4 b  = *(const float4*)(b_self + j0);
    float4 bp = *(const float4*)(bias + j0);
    b.x += bp.x; b.y += bp.y; b.z += bp.z; b.w += bp.w;

    #pragma unroll
    for (int n = 0; n < 4; ++n) {
        int v = v0 + ns * 4 + n;
        if (v < NN) {
            float4 o;
            o.x = acc[n][0] + b.x;
            o.y = acc[n][1] + b.y;
            o.z = acc[n][2] + b.z;
            o.w = acc[n][3] + b.w;
            *(float4*)(out + (size_t)v * D + j0) = o;
        }
    }
}

extern "C" void kernel_launch(void* const* d_in, const int* in_sizes, int n_in,
                              void* d_out, int out_size, void* d_ws, size_t ws_size,
                              hipStream_t stream) {
    const float* x  = (const float*)d_in[0];
    const int*   src = (const int*)d_in[1];
    const int*   dst = (const int*)d_in[2];
    const float* ew = (const float*)d_in[3];
    const float* Ws = (const float*)d_in[4];
    const float* bs = (const float*)d_in[5];
    const float* Wn = (const float*)d_in[6];
    const float* bp = (const float*)d_in[7];
    float* out = (float*)d_out;

    float* wsf   = (float*)d_ws;
    float* neigh = wsf;                          // N*128
    float* deg   = wsf + (size_t)NN * D;         // N
    float* WT    = deg + NN;                     // 256*128

    int E = in_sizes[1];

    int zn = NN * D + NN;
    int zblocks = (zn / 4 + 255) / 256;
    zero_ws_kernel<<<zblocks, 256, 0, stream>>>(wsf, zn);

    build_wt_kernel<<<(256 * 128 + 255) / 256, 256, 0, stream>>>(Ws, Wn, WT);

    scatter_kernel<<<(E + 3) / 4, 256, 0, stream>>>(x, src, dst, ew, neigh, deg, E);

    fused_out_kernel<<<(NN + 31) / 32, 256, 0, stream>>>(x, neigh, deg, WT, bs, bp, out);
}

// Round 2
// 257.363 us; speedup vs baseline: 2.9893x; 2.9893x over previous
//
#include <hip/hip_runtime.h>

#define NN 50000
#define D 128
#define EPS 1e-8f
#define NSCAN 50176          // 49 * 1024 >= NN
#define NB_SCAN 49

// ---------------- histogram of dst ----------------
__global__ __launch_bounds__(256) void hist_kernel(const int* __restrict__ dst,
                                                   int* __restrict__ count, int E) {
    int e = blockIdx.x * 256 + threadIdx.x;
    if (e < E) atomicAdd(&count[dst[e]], 1);
}

// ---------------- scan step 1: per-block exclusive scan + block sums ----------------
__global__ __launch_bounds__(1024) void scan1_kernel(const int* __restrict__ count,
                                                     int* __restrict__ offsets,
                                                     int* __restrict__ bsum) {
    __shared__ int tmp[1024];
    int t = threadIdx.x;
    int gid = blockIdx.x * 1024 + t;
    int c = count[gid];
    tmp[t] = c;
    __syncthreads();
    for (int off = 1; off < 1024; off <<= 1) {
        int v = (t >= off) ? tmp[t - off] : 0;
        __syncthreads();
        tmp[t] += v;
        __syncthreads();
    }
    offsets[gid] = tmp[t] - c;             // exclusive (partial)
    if (t == 1023) bsum[blockIdx.x] = tmp[t];
}

// ---------------- scan step 2: exclusive scan of 49 block sums ----------------
__global__ __launch_bounds__(64) void scan2_kernel(int* __restrict__ bsum) {
    __shared__ int tmp[64];
    int t = threadIdx.x;
    int b = (t < NB_SCAN) ? bsum[t] : 0;
    tmp[t] = b;
    __syncthreads();
    for (int off = 1; off < 64; off <<= 1) {
        int v = (t >= off) ? tmp[t - off] : 0;
        __syncthreads();
        tmp[t] += v;
        __syncthreads();
    }
    if (t < NB_SCAN) bsum[t] = tmp[t] - b; // exclusive
}

// ---------------- scan step 3: add block offset, init cursor ----------------
__global__ __launch_bounds__(1024) void scan3_kernel(int* __restrict__ offsets,
                                                     const int* __restrict__ bsum,
                                                     int* __restrict__ cursor) {
    int t = threadIdx.x;
    int gid = blockIdx.x * 1024 + t;
    int v = offsets[gid] + bsum[blockIdx.x];
    offsets[gid] = v;
    cursor[gid] = v;
}

// ---------------- permute edges into CSR order ----------------
__global__ __launch_bounds__(256) void csr_scatter_kernel(
        const int* __restrict__ src, const int* __restrict__ dst,
        const float* __restrict__ ew, int* __restrict__ cursor,
        int2* __restrict__ edge_sw, int E) {
    int e = blockIdx.x * 256 + threadIdx.x;
    if (e >= E) return;
    int d = dst[e];
    int pos = atomicAdd(&cursor[d], 1);
    edge_sw[pos] = make_int2(src[e], __float_as_int(ew[e]));
}

// ---------------- build WT_cat[256][128]: WT[k][j] = W_self[j][k] (k<128) else W_neigh[j][k-128]
__global__ void build_wt_kernel(const float* __restrict__ Ws,
                                const float* __restrict__ Wn,
                                float* __restrict__ WT) {
    int idx = blockIdx.x * 256 + threadIdx.x;
    if (idx < 256 * 128) {
        int k = idx >> 7;
        int j = idx & 127;
        float v = (k < 128) ? Ws[j * 128 + k] : Wn[j * 128 + (k - 128)];
        WT[idx] = v;
    }
}

// ---------------- fused gather + normalize + dual GEMM + bias ----------------
// A-tile: 32 nodes x 256 (x concat h_neigh) in LDS. 4 waves; each wave gathers 8 nodes.
__global__ __launch_bounds__(256) void fused_out_kernel(
        const float* __restrict__ x, const int* __restrict__ offsets,
        const int2* __restrict__ edge_sw, const float* __restrict__ WT,
        const float* __restrict__ b_self, const float* __restrict__ bias,
        float* __restrict__ out) {
    __shared__ float A[32][256];
    int tid = threadIdx.x;
    int v0 = blockIdx.x * 32;
    int lane = tid & 63;
    int wid = tid >> 6;

    // stage x part: 32 nodes * 128 floats = 1024 float4 (coalesced)
    for (int i = tid; i < 1024; i += 256) {
        int nn = i >> 5;
        int c4 = (i & 31) * 4;
        int v = v0 + nn;
        float4 val = make_float4(0.f, 0.f, 0.f, 0.f);
        if (v < NN) val = *(const float4*)(x + (size_t)v * D + c4);
        *(float4*)&A[nn][c4] = val;
    }

    // gather h_neigh: wave wid handles nodes wid*8 .. wid*8+7; lane owns dims 2l,2l+1
    for (int q = 0; q < 8; ++q) {
        int nn = wid * 8 + q;
        int v = v0 + nn;
        float ax = 0.f, ay = 0.f, wsum = 0.f;
        if (v < NN) {
            int beg = offsets[v];
            int end = offsets[v + 1];
            int i = beg;
            for (; i + 1 < end; i += 2) {
                int2 sw0 = edge_sw[i];
                int2 sw1 = edge_sw[i + 1];
                float w0 = __int_as_float(sw0.y);
                float w1 = __int_as_float(sw1.y);
                float2 x0 = *(const float2*)(x + (size_t)sw0.x * D + lane * 2);
                float2 x1 = *(const float2*)(x + (size_t)sw1.x * D + lane * 2);
                ax = fmaf(x0.x, w0, ax); ay = fmaf(x0.y, w0, ay);
                ax = fmaf(x1.x, w1, ax); ay = fmaf(x1.y, w1, ay);
                wsum += w0 + w1;
            }
            if (i < end) {
                int2 sw0 = edge_sw[i];
                float w0 = __int_as_float(sw0.y);
                float2 x0 = *(const float2*)(x + (size_t)sw0.x * D + lane * 2);
                ax = fmaf(x0.x, w0, ax); ay = fmaf(x0.y, w0, ay);
                wsum += w0;
            }
        }
        float inv = 1.0f / (wsum + EPS);
        A[nn][128 + lane * 2]     = ax * inv;
        A[nn][128 + lane * 2 + 1] = ay * inv;
    }
    __syncthreads();

    // GEMM: out[v][j] = sum_k A[v][k] * WT[k][j] + b_self[j] + bias[j]
    int j0 = (tid & 31) * 4;
    int ns = tid >> 5;
    float acc[4][4];
    #pragma unroll
    for (int n = 0; n < 4; ++n)
        #pragma unroll
        for (int j = 0; j < 4; ++j) acc[n][j] = 0.f;

    for (int k4 = 0; k4 < 256; k4 += 4) {
        float4 w0 = *(const float4*)(WT + (k4 + 0) * D + j0);
        float4 w1 = *(const float4*)(WT + (k4 + 1) * D + j0);
        float4 w2 = *(const float4*)(WT + (k4 + 2) * D + j0);
        float4 w3 = *(const float4*)(WT + (k4 + 3) * D + j0);
        #pragma unroll
        for (int n = 0; n < 4; ++n) {
            float4 a = *(const float4*)&A[ns * 4 + n][k4];
            acc[n][0] = fmaf(a.x, w0.x, fmaf(a.y, w1.x, fmaf(a.z, w2.x, fmaf(a.w, w3.x, acc[n][0]))));
            acc[n][1] = fmaf(a.x, w0.y, fmaf(a.y, w1.y, fmaf(a.z, w2.y, fmaf(a.w, w3.y, acc[n][1]))));
            acc[n][2] = fmaf(a.x, w0.z, fmaf(a.y, w1.z, fmaf(a.z, w2.z, fmaf(a.w, w3.z, acc[n][2]))));
            acc[n][3] = fmaf(a.x, w0.w, fmaf(a.y, w1.w, fmaf(a.z, w2.w, fmaf(a.w, w3.w, acc[n][3]))));
        }
    }

    float4 b  = *(const float4*)(b_self + j0);
    float4 bp = *(const float4*)(bias + j0);
    b.x += bp.x; b.y += bp.y; b.z += bp.z; b.w += bp.w;

    #pragma unroll
    for (int n = 0; n < 4; ++n) {
        int v = v0 + ns * 4 + n;
        if (v < NN) {
            float4 o;
            o.x = acc[n][0] + b.x;
            o.y = acc[n][1] + b.y;
            o.z = acc[n][2] + b.z;
            o.w = acc[n][3] + b.w;
            *(float4*)(out + (size_t)v * D + j0) = o;
        }
    }
}

extern "C" void kernel_launch(void* const* d_in, const int* in_sizes, int n_in,
                              void* d_out, int out_size, void* d_ws, size_t ws_size,
                              hipStream_t stream) {
    const float* x   = (const float*)d_in[0];
    const int*   src = (const int*)d_in[1];
    const int*   dst = (const int*)d_in[2];
    const float* ew  = (const float*)d_in[3];
    const float* Ws  = (const float*)d_in[4];
    const float* bs  = (const float*)d_in[5];
    const float* Wn  = (const float*)d_in[6];
    const float* bp  = (const float*)d_in[7];
    float* out = (float*)d_out;

    int E = in_sizes[1];

    // workspace layout (4B units)
    int*  wsi     = (int*)d_ws;
    int*  count   = wsi;                       // NSCAN
    int*  offsets = wsi + NSCAN;               // NSCAN (offsets[NN] lands inside, = E)
    int*  cursor  = wsi + 2 * NSCAN;           // NSCAN
    int*  bsum    = wsi + 3 * NSCAN;           // 64
    int2* edge_sw = (int2*)(wsi + 3 * NSCAN + 64);   // E int2 (8B aligned: offset mult of 8B)
    float* WT     = (float*)(wsi + 3 * NSCAN + 64 + 2 * E);  // 256*128

    hipMemsetAsync(count, 0, NSCAN * sizeof(int), stream);

    hist_kernel<<<(E + 255) / 256, 256, 0, stream>>>(dst, count, E);
    scan1_kernel<<<NB_SCAN, 1024, 0, stream>>>(count, offsets, bsum);
    scan2_kernel<<<1, 64, 0, stream>>>(bsum);
    scan3_kernel<<<NB_SCAN, 1024, 0, stream>>>(offsets, bsum, cursor);
    csr_scatter_kernel<<<(E + 255) / 256, 256, 0, stream>>>(src, dst, ew, cursor, edge_sw, E);

    build_wt_kernel<<<(256 * 128 + 255) / 256, 256, 0, stream>>>(Ws, Wn, WT);

    fused_out_kernel<<<(NN + 31) / 32, 256, 0, stream>>>(x, offsets, edge_sw, WT, bs, bp, out);
}

// Round 3
// 239.926 us; speedup vs baseline: 3.2065x; 1.0727x over previous
//
#include <hip/hip_runtime.h>

#define NN 50000
#define D 128
#define EPS 1e-8f
#define NSCAN 50176          // 1024 * 49 >= NN
#define PER_T 49

__device__ __forceinline__ unsigned short f2b(float f) {
    unsigned int u = __float_as_uint(f);
    u += 0x7FFFu + ((u >> 16) & 1u);      // round-to-nearest-even
    return (unsigned short)(u >> 16);
}
__device__ __forceinline__ float b2f(unsigned short s) {
    return __uint_as_float(((unsigned int)s) << 16);
}

// ---------------- histogram of dst ----------------
__global__ __launch_bounds__(256) void hist_kernel(const int* __restrict__ dst,
                                                   int* __restrict__ count, int E) {
    int e = blockIdx.x * 256 + threadIdx.x;
    if (e < E) atomicAdd(&count[dst[e]], 1);
}

// ---------------- single-block scan of NSCAN counts -> offsets, cursor ----------------
__global__ __launch_bounds__(1024) void scan_all_kernel(const int* __restrict__ count,
                                                        int* __restrict__ offsets,
                                                        int* __restrict__ cursor) {
    __shared__ int sums[1024];
    int t = threadIdx.x;
    int base = t * PER_T;
    int loc[PER_T];
    int s = 0;
    #pragma unroll
    for (int k = 0; k < PER_T; ++k) { loc[k] = s; s += count[base + k]; }
    sums[t] = s;
    __syncthreads();
    for (int off = 1; off < 1024; off <<= 1) {
        int v = (t >= off) ? sums[t - off] : 0;
        __syncthreads();
        sums[t] += v;
        __syncthreads();
    }
    int pre = sums[t] - s;   // exclusive prefix of this thread's chunk
    #pragma unroll
    for (int k = 0; k < PER_T; ++k) {
        int o = pre + loc[k];
        offsets[base + k] = o;
        cursor[base + k] = o;
    }
}

// ---------------- permute edges into CSR order ----------------
__global__ __launch_bounds__(256) void csr_scatter_kernel(
        const int* __restrict__ src, const int* __restrict__ dst,
        const float* __restrict__ ew, int* __restrict__ cursor,
        int2* __restrict__ edge_sw, int E) {
    int e = blockIdx.x * 256 + threadIdx.x;
    if (e >= E) return;
    int d = dst[e];
    int pos = atomicAdd(&cursor[d], 1);
    edge_sw[pos] = make_int2(src[e], __float_as_int(ew[e]));
}

// ---------------- x -> bf16 copy (for gather path only) ----------------
__global__ __launch_bounds__(256) void cvt_bf16_kernel(const float* __restrict__ x,
                                                       ushort* __restrict__ xb, int n4) {
    int i = blockIdx.x * 256 + threadIdx.x;
    if (i < n4) {
        float4 v = ((const float4*)x)[i];
        ushort4 o;
        o.x = f2b(v.x); o.y = f2b(v.y); o.z = f2b(v.z); o.w = f2b(v.w);
        ((ushort4*)xb)[i] = o;
    }
}

// ---------------- build WT_cat[256][128] ----------------
__global__ void build_wt_kernel(const float* __restrict__ Ws,
                                const float* __restrict__ Wn,
                                float* __restrict__ WT) {
    int idx = blockIdx.x * 256 + threadIdx.x;
    if (idx < 256 * 128) {
        int k = idx >> 7;
        int j = idx & 127;
        float v = (k < 128) ? Ws[j * 128 + k] : Wn[j * 128 + (k - 128)];
        WT[idx] = v;
    }
}

// ---------------- fused gather(bf16) + normalize + dual GEMM + bias ----------------
__global__ __launch_bounds__(256) void fused_out_kernel(
        const float* __restrict__ x, const ushort* __restrict__ xb,
        const int* __restrict__ offsets, const int2* __restrict__ edge_sw,
        const float* __restrict__ WT, const float* __restrict__ b_self,
        const float* __restrict__ bias, float* __restrict__ out) {
    __shared__ float A[32][256];
    int tid = threadIdx.x;
    int v0 = blockIdx.x * 32;
    int lane = tid & 63;
    int wid = tid >> 6;
    int half = lane >> 5;    // 0: even edges of chunk, 1: odd
    int l32 = lane & 31;     // dim group: dims l32*4 .. l32*4+3

    // stage fp32 x part: 32 nodes * 128 floats = 1024 float4 (coalesced)
    for (int i = tid; i < 1024; i += 256) {
        int nn = i >> 5;
        int c4 = (i & 31) * 4;
        int v = v0 + nn;
        float4 val = make_float4(0.f, 0.f, 0.f, 0.f);
        if (v < NN) val = *(const float4*)(x + (size_t)v * D + c4);
        *(float4*)&A[nn][c4] = val;
    }

    // gather h_neigh in bf16: wave wid owns nodes wid*8..wid*8+7
    for (int q = 0; q < 8; ++q) {
        int nn = wid * 8 + q;
        int v = v0 + nn;
        float4 acc = make_float4(0.f, 0.f, 0.f, 0.f);
        float wsum = 0.f;
        if (v < NN) {
            int beg = offsets[v];
            int end = offsets[v + 1];
            int cnt = end - beg;
            int nmain = cnt & ~3;
            for (int i = beg; i < beg + nmain; i += 4) {
                int2 mA = edge_sw[i + half];         // edges i+0 / i+1
                int2 mB = edge_sw[i + 2 + half];     // edges i+2 / i+3
                float wA = __int_as_float(mA.y);
                float wB = __int_as_float(mB.y);
                ushort4 xA = *((const ushort4*)(xb + (size_t)mA.x * D) + l32);
                ushort4 xB = *((const ushort4*)(xb + (size_t)mB.x * D) + l32);
                acc.x = fmaf(b2f(xA.x), wA, acc.x);
                acc.y = fmaf(b2f(xA.y), wA, acc.y);
                acc.z = fmaf(b2f(xA.z), wA, acc.z);
                acc.w = fmaf(b2f(xA.w), wA, acc.w);
                acc.x = fmaf(b2f(xB.x), wB, acc.x);
                acc.y = fmaf(b2f(xB.y), wB, acc.y);
                acc.z = fmaf(b2f(xB.z), wB, acc.z);
                acc.w = fmaf(b2f(xB.w), wB, acc.w);
                wsum += wA + wB;
            }
            if (half == 0) {
                for (int i = beg + nmain; i < end; ++i) {
                    int2 m = edge_sw[i];
                    float w = __int_as_float(m.y);
                    ushort4 xm = *((const ushort4*)(xb + (size_t)m.x * D) + l32);
                    acc.x = fmaf(b2f(xm.x), w, acc.x);
                    acc.y = fmaf(b2f(xm.y), w, acc.y);
                    acc.z = fmaf(b2f(xm.z), w, acc.z);
                    acc.w = fmaf(b2f(xm.w), w, acc.w);
                    wsum += w;
                }
            }
        }
        // combine even/odd halves (lane i <-> lane i+32)
        acc.x += __shfl_xor(acc.x, 32);
        acc.y += __shfl_xor(acc.y, 32);
        acc.z += __shfl_xor(acc.z, 32);
        acc.w += __shfl_xor(acc.w, 32);
        wsum  += __shfl_xor(wsum, 32);
        if (half == 0) {
            float inv = 1.0f / (wsum + EPS);
            *(float4*)&A[nn][128 + l32 * 4] =
                make_float4(acc.x * inv, acc.y * inv, acc.z * inv, acc.w * inv);
        }
    }
    __syncthreads();

    // GEMM: out[v][j] = sum_k A[v][k] * WT[k][j] + b_self[j] + bias[j]
    int j0 = (tid & 31) * 4;
    int ns = tid >> 5;
    float acc[4][4];
    #pragma unroll
    for (int n = 0; n < 4; ++n)
        #pragma unroll
        for (int j = 0; j < 4; ++j) acc[n][j] = 0.f;

    for (int k4 = 0; k4 < 256; k4 += 4) {
        float4 w0 = *(const float4*)(WT + (k4 + 0) * D + j0);
        float4 w1 = *(const float4*)(WT + (k4 + 1) * D + j0);
        float4 w2 = *(const float4*)(WT + (k4 + 2) * D + j0);
        float4 w3 = *(const float4*)(WT + (k4 + 3) * D + j0);
        #pragma unroll
        for (int n = 0; n < 4; ++n) {
            float4 a = *(const float4*)&A[ns * 4 + n][k4];
            acc[n][0] = fmaf(a.x, w0.x, fmaf(a.y, w1.x, fmaf(a.z, w2.x, fmaf(a.w, w3.x, acc[n][0]))));
            acc[n][1] = fmaf(a.x, w0.y, fmaf(a.y, w1.y, fmaf(a.z, w2.y, fmaf(a.w, w3.y, acc[n][1]))));
            acc[n][2] = fmaf(a.x, w0.z, fmaf(a.y, w1.z, fmaf(a.z, w2.z, fmaf(a.w, w3.z, acc[n][2]))));
            acc[n][3] = fmaf(a.x, w0.w, fmaf(a.y, w1.w, fmaf(a.z, w2.w, fmaf(a.w, w3.w, acc[n][3]))));
        }
    }

    float4 b  = *(const float4*)(b_self + j0);
    float4 bp = *(const float4*)(bias + j0);
    b.x += bp.x; b.y += bp.y; b.z += bp.z; b.w += bp.w;

    #pragma unroll
    for (int n = 0; n < 4; ++n) {
        int v = v0 + ns * 4 + n;
        if (v < NN) {
            float4 o;
            o.x = acc[n][0] + b.x;
            o.y = acc[n][1] + b.y;
            o.z = acc[n][2] + b.z;
            o.w = acc[n][3] + b.w;
            *(float4*)(out + (size_t)v * D + j0) = o;
        }
    }
}

extern "C" void kernel_launch(void* const* d_in, const int* in_sizes, int n_in,
                              void* d_out, int out_size, void* d_ws, size_t ws_size,
                              hipStream_t stream) {
    const float* x   = (const float*)d_in[0];
    const int*   src = (const int*)d_in[1];
    const int*   dst = (const int*)d_in[2];
    const float* ew  = (const float*)d_in[3];
    const float* Ws  = (const float*)d_in[4];
    const float* bs  = (const float*)d_in[5];
    const float* Wn  = (const float*)d_in[6];
    const float* bp  = (const float*)d_in[7];
    float* out = (float*)d_out;

    int E = in_sizes[1];

    // workspace layout (4B units)
    int*  wsi     = (int*)d_ws;
    int*  count   = wsi;                       // NSCAN
    int*  offsets = wsi + NSCAN;               // NSCAN
    int*  cursor  = wsi + 2 * NSCAN;           // NSCAN
    int2* edge_sw = (int2*)(wsi + 3 * NSCAN);  // E int2 (3*NSCAN*4 % 8 == 0)
    float* WT     = (float*)(wsi + 3 * NSCAN + 2 * E);        // 256*128 floats
    ushort* xb    = (ushort*)(WT + 256 * 128);                // NN*D bf16

    hipMemsetAsync(count, 0, NSCAN * sizeof(int), stream);

    hist_kernel<<<(E + 255) / 256, 256, 0, stream>>>(dst, count, E);
    scan_all_kernel<<<1, 1024, 0, stream>>>(count, offsets, cursor);
    csr_scatter_kernel<<<(E + 255) / 256, 256, 0, stream>>>(src, dst, ew, cursor, edge_sw, E);

    cvt_bf16_kernel<<<(NN * D / 4 + 255) / 256, 256, 0, stream>>>(x, xb, NN * D / 4);
    build_wt_kernel<<<(256 * 128 + 255) / 256, 256, 0, stream>>>(Ws, Wn, WT);

    fused_out_kernel<<<(NN + 31) / 32, 256, 0, stream>>>(x, xb, offsets, edge_sw, WT, bs, bp, out);
}

// Round 8
// 230.844 us; speedup vs baseline: 3.3327x; 1.0393x over previous
//
#include <hip/hip_runtime.h>

#define NN 50000
#define D 128
#define EPS 1e-8f
#define NSCAN 50176          // 49 * 1024 >= NN
#define NB_SCAN 49

__device__ __forceinline__ unsigned short f2b(float f) {
    unsigned int u = __float_as_uint(f);
    u += 0x7FFFu + ((u >> 16) & 1u);      // round-to-nearest-even
    return (unsigned short)(u >> 16);
}
__device__ __forceinline__ float b2f(unsigned short s) {
    return __uint_as_float(((unsigned int)s) << 16);
}

// ---------------- histogram of dst ----------------
__global__ __launch_bounds__(256) void hist_kernel(const int* __restrict__ dst,
                                                   int* __restrict__ count, int E) {
    int e = blockIdx.x * 256 + threadIdx.x;
    if (e < E) atomicAdd(&count[dst[e]], 1);
}

// ---------------- scan step 1: per-block exclusive scan + block sums ----------------
__global__ __launch_bounds__(1024) void scan1_kernel(const int* __restrict__ count,
                                                     int* __restrict__ offsets,
                                                     int* __restrict__ bsum) {
    __shared__ int tmp[1024];
    int t = threadIdx.x;
    int gid = blockIdx.x * 1024 + t;
    int c = count[gid];
    tmp[t] = c;
    __syncthreads();
    for (int off = 1; off < 1024; off <<= 1) {
        int v = (t >= off) ? tmp[t - off] : 0;
        __syncthreads();
        tmp[t] += v;
        __syncthreads();
    }
    offsets[gid] = tmp[t] - c;
    if (t == 1023) bsum[blockIdx.x] = tmp[t];
}

// ---------------- scan step 2: exclusive scan of 49 block sums ----------------
__global__ __launch_bounds__(64) void scan2_kernel(int* __restrict__ bsum) {
    __shared__ int tmp[64];
    int t = threadIdx.x;
    int b = (t < NB_SCAN) ? bsum[t] : 0;
    tmp[t] = b;
    __syncthreads();
    for (int off = 1; off < 64; off <<= 1) {
        int v = (t >= off) ? tmp[t - off] : 0;
        __syncthreads();
        tmp[t] += v;
        __syncthreads();
    }
    if (t < NB_SCAN) bsum[t] = tmp[t] - b;
}

// ---------------- scan step 3: add block offset, init cursor ----------------
__global__ __launch_bounds__(1024) void scan3_kernel(int* __restrict__ offsets,
                                                     const int* __restrict__ bsum,
                                                     int* __restrict__ cursor) {
    int t = threadIdx.x;
    int gid = blockIdx.x * 1024 + t;
    int v = offsets[gid] + bsum[blockIdx.x];
    offsets[gid] = v;
    cursor[gid] = v;
}

// ---------------- permute edges into CSR order ----------------
__global__ __launch_bounds__(256) void csr_scatter_kernel(
        const int* __restrict__ src, const int* __restrict__ dst,
        const float* __restrict__ ew, int* __restrict__ cursor,
        int2* __restrict__ edge_sw, int E) {
    int e = blockIdx.x * 256 + threadIdx.x;
    if (e >= E) return;
    int d = dst[e];
    int pos = atomicAdd(&cursor[d], 1);
    edge_sw[pos] = make_int2(src[e], __float_as_int(ew[e]));
}

// ---------------- x -> bf16 copy (gather path only) ----------------
__global__ __launch_bounds__(256) void cvt_bf16_kernel(const float* __restrict__ x,
                                                       ushort* __restrict__ xb, int n4) {
    int i = blockIdx.x * 256 + threadIdx.x;
    if (i < n4) {
        float4 v = ((const float4*)x)[i];
        ushort4 o;
        o.x = f2b(v.x); o.y = f2b(v.y); o.z = f2b(v.z); o.w = f2b(v.w);
        ((ushort4*)xb)[i] = o;
    }
}

// ---------------- build WT_cat[256][128]: WT[k][j] = W_self[j][k] (k<128) else W_neigh[j][k-128]
__global__ void build_wt_kernel(const float* __restrict__ Ws,
                                const float* __restrict__ Wn,
                                float* __restrict__ WT) {
    int idx = blockIdx.x * 256 + threadIdx.x;
    if (idx < 256 * 128) {
        int k = idx >> 7;
        int j = idx & 127;
        float v = (k < 128) ? Ws[j * 128 + k] : Wn[j * 128 + (k - 128)];
        WT[idx] = v;
    }
}

// ---------------- fused gather(bf16) + normalize + dual GEMM + bias ----------------
// LDS holds ONLY h_neigh (16KB) -> 2x occupancy vs R3. Self-path x read from global in GEMM.
__global__ __launch_bounds__(256) void fused_out_kernel(
        const float* __restrict__ x, const ushort* __restrict__ xb,
        const int* __restrict__ offsets, const int2* __restrict__ edge_sw,
        const float* __restrict__ WT, const float* __restrict__ b_self,
        const float* __restrict__ bias, float* __restrict__ out) {
    __shared__ float HN[32][128];
    int tid = threadIdx.x;
    int v0 = blockIdx.x * 32;
    int lane = tid & 63;
    int wid = tid >> 6;
    int half = lane >> 5;
    int l32 = lane & 31;

    // gather h_neigh in bf16 (R3 verbatim): wave wid owns nodes wid*8..wid*8+7
    for (int q = 0; q < 8; ++q) {
        int nn = wid * 8 + q;
        int v = v0 + nn;
        float4 acc = make_float4(0.f, 0.f, 0.f, 0.f);
        float wsum = 0.f;
        if (v < NN) {
            int beg = offsets[v];
            int end = offsets[v + 1];
            int cnt = end - beg;
            int nmain = cnt & ~3;
            for (int i = beg; i < beg + nmain; i += 4) {
                int2 mA = edge_sw[i + half];
                int2 mB = edge_sw[i + 2 + half];
                float wA = __int_as_float(mA.y);
                float wB = __int_as_float(mB.y);
                ushort4 xA = *((const ushort4*)(xb + (size_t)mA.x * D) + l32);
                ushort4 xB = *((const ushort4*)(xb + (size_t)mB.x * D) + l32);
                acc.x = fmaf(b2f(xA.x), wA, acc.x);
                acc.y = fmaf(b2f(xA.y), wA, acc.y);
                acc.z = fmaf(b2f(xA.z), wA, acc.z);
                acc.w = fmaf(b2f(xA.w), wA, acc.w);
                acc.x = fmaf(b2f(xB.x), wB, acc.x);
                acc.y = fmaf(b2f(xB.y), wB, acc.y);
                acc.z = fmaf(b2f(xB.z), wB, acc.z);
                acc.w = fmaf(b2f(xB.w), wB, acc.w);
                wsum += wA + wB;
            }
            if (half == 0) {
                for (int i = beg + nmain; i < end; ++i) {
                    int2 m = edge_sw[i];
                    float w = __int_as_float(m.y);
                    ushort4 xm = *((const ushort4*)(xb + (size_t)m.x * D) + l32);
                    acc.x = fmaf(b2f(xm.x), w, acc.x);
                    acc.y = fmaf(b2f(xm.y), w, acc.y);
                    acc.z = fmaf(b2f(xm.z), w, acc.z);
                    acc.w = fmaf(b2f(xm.w), w, acc.w);
                    wsum += w;
                }
            }
        }
        acc.x += __shfl_xor(acc.x, 32);
        acc.y += __shfl_xor(acc.y, 32);
        acc.z += __shfl_xor(acc.z, 32);
        acc.w += __shfl_xor(acc.w, 32);
        wsum  += __shfl_xor(wsum, 32);
        if (half == 0) {
            float inv = 1.0f / (wsum + EPS);
            *(float4*)&HN[nn][l32 * 4] =
                make_float4(acc.x * inv, acc.y * inv, acc.z * inv, acc.w * inv);
        }
    }
    __syncthreads();

    // GEMM: out[v][j] = sum_k x[v][k]*WT[k][j] + sum_k hn[v][k]*WT[128+k][j] + biases
    int j0 = (tid & 31) * 4;
    int ns = tid >> 5;
    float acc[4][4];
    #pragma unroll
    for (int n = 0; n < 4; ++n)
        #pragma unroll
        for (int j = 0; j < 4; ++j) acc[n][j] = 0.f;

    int rowc[4];
    #pragma unroll
    for (int n = 0; n < 4; ++n) {
        int rv = v0 + ns * 4 + n;
        rowc[n] = (rv < NN) ? rv : (NN - 1);   // clamped read; store is guarded
    }

    // self half: A from global x (per-wave broadcast, L1-resident)
    for (int k4 = 0; k4 < 128; k4 += 4) {
        float4 w0 = *(const float4*)(WT + (k4 + 0) * D + j0);
        float4 w1 = *(const float4*)(WT + (k4 + 1) * D + j0);
        float4 w2 = *(const float4*)(WT + (k4 + 2) * D + j0);
        float4 w3 = *(const float4*)(WT + (k4 + 3) * D + j0);
        #pragma unroll
        for (int n = 0; n < 4; ++n) {
            float4 a = *(const float4*)(x + (size_t)rowc[n] * D + k4);
            acc[n][0] = fmaf(a.x, w0.x, fmaf(a.y, w1.x, fmaf(a.z, w2.x, fmaf(a.w, w3.x, acc[n][0]))));
            acc[n][1] = fmaf(a.x, w0.y, fmaf(a.y, w1.y, fmaf(a.z, w2.y, fmaf(a.w, w3.y, acc[n][1]))));
            acc[n][2] = fmaf(a.x, w0.z, fmaf(a.y, w1.z, fmaf(a.z, w2.z, fmaf(a.w, w3.z, acc[n][2]))));
            acc[n][3] = fmaf(a.x, w0.w, fmaf(a.y, w1.w, fmaf(a.z, w2.w, fmaf(a.w, w3.w, acc[n][3]))));
        }
    }
    // neigh half: A from LDS HN
    for (int k4 = 0; k4 < 128; k4 += 4) {
        float4 w0 = *(const float4*)(WT + (128 + k4 + 0) * D + j0);
        float4 w1 = *(const float4*)(WT + (128 + k4 + 1) * D + j0);
        float4 w2 = *(const float4*)(WT + (128 + k4 + 2) * D + j0);
        float4 w3 = *(const float4*)(WT + (128 + k4 + 3) * D + j0);
        #pragma unroll
        for (int n = 0; n < 4; ++n) {
            float4 a = *(const float4*)&HN[ns * 4 + n][k4];
            acc[n][0] = fmaf(a.x, w0.x, fmaf(a.y, w1.x, fmaf(a.z, w2.x, fmaf(a.w, w3.x, acc[n][0]))));
            acc[n][1] = fmaf(a.x, w0.y, fmaf(a.y, w1.y, fmaf(a.z, w2.y, fmaf(a.w, w3.y, acc[n][1]))));
            acc[n][2] = fmaf(a.x, w0.z, fmaf(a.y, w1.z, fmaf(a.z, w2.z, fmaf(a.w, w3.z, acc[n][2]))));
            acc[n][3] = fmaf(a.x, w0.w, fmaf(a.y, w1.w, fmaf(a.z, w2.w, fmaf(a.w, w3.w, acc[n][3]))));
        }
    }

    float4 b  = *(const float4*)(b_self + j0);
    float4 bp = *(const float4*)(bias + j0);
    b.x += bp.x; b.y += bp.y; b.z += bp.z; b.w += bp.w;

    #pragma unroll
    for (int n = 0; n < 4; ++n) {
        int v = v0 + ns * 4 + n;
        if (v < NN) {
            float4 o;
            o.x = acc[n][0] + b.x;
            o.y = acc[n][1] + b.y;
            o.z = acc[n][2] + b.z;
            o.w = acc[n][3] + b.w;
            *(float4*)(out + (size_t)v * D + j0) = o;
        }
    }
}

extern "C" void kernel_launch(void* const* d_in, const int* in_sizes, int n_in,
                              void* d_out, int out_size, void* d_ws, size_t ws_size,
                              hipStream_t stream) {
    const float* x   = (const float*)d_in[0];
    const int*   src = (const int*)d_in[1];
    const int*   dst = (const int*)d_in[2];
    const float* ew  = (const float*)d_in[3];
    const float* Ws  = (const float*)d_in[4];
    const float* bs  = (const float*)d_in[5];
    const float* Wn  = (const float*)d_in[6];
    const float* bp  = (const float*)d_in[7];
    float* out = (float*)d_out;

    int E = in_sizes[1];

    // workspace layout (4B units)
    int*  wsi     = (int*)d_ws;
    int*  count   = wsi;                       // NSCAN
    int*  offsets = wsi + NSCAN;               // NSCAN
    int*  cursor  = wsi + 2 * NSCAN;           // NSCAN
    int*  bsum    = wsi + 3 * NSCAN;           // 64
    int2* edge_sw = (int2*)(wsi + 3 * NSCAN + 64);             // E int2
    float* WT     = (float*)(wsi + 3 * NSCAN + 64 + 2 * E);    // 256*128 floats
    ushort* xb    = (ushort*)(WT + 256 * 128);                 // NN*D bf16

    hipMemsetAsync(count, 0, NSCAN * sizeof(int), stream);

    hist_kernel<<<(E + 255) / 256, 256, 0, stream>>>(dst, count, E);
    scan1_kernel<<<NB_SCAN, 1024, 0, stream>>>(count, offsets, bsum);
    scan2_kernel<<<1, 64, 0, stream>>>(bsum);
    scan3_kernel<<<NB_SCAN, 1024, 0, stream>>>(offsets, bsum, cursor);
    csr_scatter_kernel<<<(E + 255) / 256, 256, 0, stream>>>(src, dst, ew, cursor, edge_sw, E);

    cvt_bf16_kernel<<<(NN * D / 4 + 255) / 256, 256, 0, stream>>>(x, xb, NN * D / 4);
    build_wt_kernel<<<(256 * 128 + 255) / 256, 256, 0, stream>>>(Ws, Wn, WT);

    fused_out_kernel<<<(NN + 31) / 32, 256, 0, stream>>>(x, xb, offsets, edge_sw,
                                                         WT, bs, bp, out);
}

// Round 9
// 208.151 us; speedup vs baseline: 3.6960x; 1.1090x over previous
//
#include <hip/hip_runtime.h>

#define NN 50000
#define D 128
#define EPS 1e-8f
#define NSCAN 50176          // 49 * 1024 >= NN
#define NB_SCAN 49

__device__ __forceinline__ unsigned short f2b(float f) {
    unsigned int u = __float_as_uint(f);
    u += 0x7FFFu + ((u >> 16) & 1u);      // round-to-nearest-even
    return (unsigned short)(u >> 16);
}
__device__ __forceinline__ float b2f(unsigned short s) {
    return __uint_as_float(((unsigned int)s) << 16);
}

// ---------------- prep: dst histogram + x->bf16 + WT build (fused) ----------------
__global__ __launch_bounds__(256) void prep_kernel(
        const int* __restrict__ dst, int* __restrict__ count,
        const float* __restrict__ x, ushort* __restrict__ xb,
        const float* __restrict__ Ws, const float* __restrict__ Wn,
        float* __restrict__ WT, int E) {
    int i = blockIdx.x * 256 + threadIdx.x;
    if (i < E) atomicAdd(&count[dst[i]], 1);
    if (i < NN * D / 4) {
        float4 v = ((const float4*)x)[i];
        ushort4 o;
        o.x = f2b(v.x); o.y = f2b(v.y); o.z = f2b(v.z); o.w = f2b(v.w);
        ((ushort4*)xb)[i] = o;
    }
    if (i < 256 * 128) {
        int k = i >> 7;
        int j = i & 127;
        float v = (k < 128) ? Ws[j * 128 + k] : Wn[j * 128 + (k - 128)];
        WT[i] = v;
    }
}

// ---------------- scan step 1: pad counts to even, per-block exclusive scan ----------------
__global__ __launch_bounds__(1024) void scan1_kernel(const int* __restrict__ count,
                                                     int* __restrict__ offsets,
                                                     int* __restrict__ bsum) {
    __shared__ int tmp[1024];
    int t = threadIdx.x;
    int gid = blockIdx.x * 1024 + t;
    int c = (count[gid] + 1) & ~1;        // pad each node to even edge count
    tmp[t] = c;
    __syncthreads();
    for (int off = 1; off < 1024; off <<= 1) {
        int v = (t >= off) ? tmp[t - off] : 0;
        __syncthreads();
        tmp[t] += v;
        __syncthreads();
    }
    offsets[gid] = tmp[t] - c;
    if (t == 1023) bsum[blockIdx.x] = tmp[t];
}

// ---------------- scan step 2+3: scan block sums (redundant per block) + add + cursor ----------------
__global__ __launch_bounds__(1024) void scan23_kernel(int* __restrict__ offsets,
                                                      const int* __restrict__ bsum,
                                                      int* __restrict__ cursor) {
    __shared__ int bs[64];
    int t = threadIdx.x;
    if (t < 64) {
        int orig = (t < NB_SCAN) ? bsum[t] : 0;
        int v = orig;
        #pragma unroll
        for (int off = 1; off < 64; off <<= 1) {
            int u = __shfl_up(v, off);
            if (t >= off) v += u;
        }
        bs[t] = v - orig;    // exclusive
    }
    __syncthreads();
    int gid = blockIdx.x * 1024 + t;
    int val = offsets[gid] + bs[blockIdx.x];
    offsets[gid] = val;
    cursor[gid] = val;
}

// ---------------- permute edges into CSR order (pad slots stay zeroed) ----------------
__global__ __launch_bounds__(256) void csr_scatter_kernel(
        const int* __restrict__ src, const int* __restrict__ dst,
        const float* __restrict__ ew, int* __restrict__ cursor,
        int2* __restrict__ edge_sw, int E) {
    int e = blockIdx.x * 256 + threadIdx.x;
    if (e >= E) return;
    int d = dst[e];
    int pos = atomicAdd(&cursor[d], 1);
    edge_sw[pos] = make_int2(src[e], __float_as_int(ew[e]));
}

// ---------------- fused gather(bf16, 8-edge chunks) + dual GEMM + bias ----------------
__global__ __launch_bounds__(256) void fused_out_kernel(
        const float* __restrict__ x, const ushort* __restrict__ xb,
        const int* __restrict__ offsets, const int2* __restrict__ edge_sw,
        const float* __restrict__ WT, const float* __restrict__ b_self,
        const float* __restrict__ bias, float* __restrict__ out) {
    __shared__ float HN[32][128];
    int tid = threadIdx.x;
    int v0 = blockIdx.x * 32;
    int lane = tid & 63;
    int wid = tid >> 6;
    int half = lane >> 5;
    int l32 = lane & 31;

    // gather h_neigh: wave wid owns nodes wid*8..wid*8+7; counts are even (padded, w=0 pads)
    for (int q = 0; q < 8; ++q) {
        int nn = wid * 8 + q;
        int v = v0 + nn;
        float4 acc = make_float4(0.f, 0.f, 0.f, 0.f);
        float wsum = 0.f;
        if (v < NN) {
            int beg = offsets[v];
            int end = offsets[v + 1];
            int cnt = end - beg;               // even
            int i = beg;
            int n8 = cnt & ~7;
            for (; i < beg + n8; i += 8) {
                // half h handles edges i+4h .. i+4h+3 (16B-aligned int4 metas)
                int4 mA = *(const int4*)(edge_sw + i + 4 * half);
                int4 mB = *(const int4*)(edge_sw + i + 4 * half + 2);
                float w0 = __int_as_float(mA.y), w1 = __int_as_float(mA.w);
                float w2 = __int_as_float(mB.y), w3 = __int_as_float(mB.w);
                ushort4 r0 = *((const ushort4*)(xb + (size_t)mA.x * D) + l32);
                ushort4 r1 = *((const ushort4*)(xb + (size_t)mA.z * D) + l32);
                ushort4 r2 = *((const ushort4*)(xb + (size_t)mB.x * D) + l32);
                ushort4 r3 = *((const ushort4*)(xb + (size_t)mB.z * D) + l32);
                acc.x = fmaf(b2f(r0.x), w0, acc.x); acc.y = fmaf(b2f(r0.y), w0, acc.y);
                acc.z = fmaf(b2f(r0.z), w0, acc.z); acc.w = fmaf(b2f(r0.w), w0, acc.w);
                acc.x = fmaf(b2f(r1.x), w1, acc.x); acc.y = fmaf(b2f(r1.y), w1, acc.y);
                acc.z = fmaf(b2f(r1.z), w1, acc.z); acc.w = fmaf(b2f(r1.w), w1, acc.w);
                acc.x = fmaf(b2f(r2.x), w2, acc.x); acc.y = fmaf(b2f(r2.y), w2, acc.y);
                acc.z = fmaf(b2f(r2.z), w2, acc.z); acc.w = fmaf(b2f(r2.w), w2, acc.w);
                acc.x = fmaf(b2f(r3.x), w3, acc.x); acc.y = fmaf(b2f(r3.y), w3, acc.y);
                acc.z = fmaf(b2f(r3.z), w3, acc.z); acc.w = fmaf(b2f(r3.w), w3, acc.w);
                wsum += (w0 + w1) + (w2 + w3);
            }
            if (cnt & 4) {
                // half h handles edges i+2h, i+2h+1
                int4 mA = *(const int4*)(edge_sw + i + 2 * half);
                float w0 = __int_as_float(mA.y), w1 = __int_as_float(mA.w);
                ushort4 r0 = *((const ushort4*)(xb + (size_t)mA.x * D) + l32);
                ushort4 r1 = *((const ushort4*)(xb + (size_t)mA.z * D) + l32);
                acc.x = fmaf(b2f(r0.x), w0, acc.x); acc.y = fmaf(b2f(r0.y), w0, acc.y);
                acc.z = fmaf(b2f(r0.z), w0, acc.z); acc.w = fmaf(b2f(r0.w), w0, acc.w);
                acc.x = fmaf(b2f(r1.x), w1, acc.x); acc.y = fmaf(b2f(r1.y), w1, acc.y);
                acc.z = fmaf(b2f(r1.z), w1, acc.z); acc.w = fmaf(b2f(r1.w), w1, acc.w);
                wsum += w0 + w1;
                i += 4;
            }
            if ((cnt & 2) && half == 0) {
                // last 2 edges (may include the zero pad)
                int4 mA = *(const int4*)(edge_sw + i);
                float w0 = __int_as_float(mA.y), w1 = __int_as_float(mA.w);
                ushort4 r0 = *((const ushort4*)(xb + (size_t)mA.x * D) + l32);
                ushort4 r1 = *((const ushort4*)(xb + (size_t)mA.z * D) + l32);
                acc.x = fmaf(b2f(r0.x), w0, acc.x); acc.y = fmaf(b2f(r0.y), w0, acc.y);
                acc.z = fmaf(b2f(r0.z), w0, acc.z); acc.w = fmaf(b2f(r0.w), w0, acc.w);
                acc.x = fmaf(b2f(r1.x), w1, acc.x); acc.y = fmaf(b2f(r1.y), w1, acc.y);
                acc.z = fmaf(b2f(r1.z), w1, acc.z); acc.w = fmaf(b2f(r1.w), w1, acc.w);
                wsum += w0 + w1;
            }
        }
        acc.x += __shfl_xor(acc.x, 32);
        acc.y += __shfl_xor(acc.y, 32);
        acc.z += __shfl_xor(acc.z, 32);
        acc.w += __shfl_xor(acc.w, 32);
        wsum  += __shfl_xor(wsum, 32);
        if (half == 0) {
            float inv = 1.0f / (wsum + EPS);
            *(float4*)&HN[nn][l32 * 4] =
                make_float4(acc.x * inv, acc.y * inv, acc.z * inv, acc.w * inv);
        }
    }
    __syncthreads();

    // GEMM: out[v][j] = sum_k x[v][k]*WT[k][j] + sum_k hn[v][k]*WT[128+k][j] + biases
    int j0 = (tid & 31) * 4;
    int ns = tid >> 5;
    float acc[4][4];
    #pragma unroll
    for (int n = 0; n < 4; ++n)
        #pragma unroll
        for (int j = 0; j < 4; ++j) acc[n][j] = 0.f;

    int rowc[4];
    #pragma unroll
    for (int n = 0; n < 4; ++n) {
        int rv = v0 + ns * 4 + n;
        rowc[n] = (rv < NN) ? rv : (NN - 1);   // clamped read; store is guarded
    }

    // self half: A from global x (per-wave broadcast, L1/L2-resident)
    for (int k4 = 0; k4 < 128; k4 += 4) {
        float4 w0 = *(const float4*)(WT + (k4 + 0) * D + j0);
        float4 w1 = *(const float4*)(WT + (k4 + 1) * D + j0);
        float4 w2 = *(const float4*)(WT + (k4 + 2) * D + j0);
        float4 w3 = *(const float4*)(WT + (k4 + 3) * D + j0);
        #pragma unroll
        for (int n = 0; n < 4; ++n) {
            float4 a = *(const float4*)(x + (size_t)rowc[n] * D + k4);
            acc[n][0] = fmaf(a.x, w0.x, fmaf(a.y, w1.x, fmaf(a.z, w2.x, fmaf(a.w, w3.x, acc[n][0]))));
            acc[n][1] = fmaf(a.x, w0.y, fmaf(a.y, w1.y, fmaf(a.z, w2.y, fmaf(a.w, w3.y, acc[n][1]))));
            acc[n][2] = fmaf(a.x, w0.z, fmaf(a.y, w1.z, fmaf(a.z, w2.z, fmaf(a.w, w3.z, acc[n][2]))));
            acc[n][3] = fmaf(a.x, w0.w, fmaf(a.y, w1.w, fmaf(a.z, w2.w, fmaf(a.w, w3.w, acc[n][3]))));
        }
    }
    // neigh half: A from LDS HN
    for (int k4 = 0; k4 < 128; k4 += 4) {
        float4 w0 = *(const float4*)(WT + (128 + k4 + 0) * D + j0);
        float4 w1 = *(const float4*)(WT + (128 + k4 + 1) * D + j0);
        float4 w2 = *(const float4*)(WT + (128 + k4 + 2) * D + j0);
        float4 w3 = *(const float4*)(WT + (128 + k4 + 3) * D + j0);
        #pragma unroll
        for (int n = 0; n < 4; ++n) {
            float4 a = *(const float4*)&HN[ns * 4 + n][k4];
            acc[n][0] = fmaf(a.x, w0.x, fmaf(a.y, w1.x, fmaf(a.z, w2.x, fmaf(a.w, w3.x, acc[n][0]))));
            acc[n][1] = fmaf(a.x, w0.y, fmaf(a.y, w1.y, fmaf(a.z, w2.y, fmaf(a.w, w3.y, acc[n][1]))));
            acc[n][2] = fmaf(a.x, w0.z, fmaf(a.y, w1.z, fmaf(a.z, w2.z, fmaf(a.w, w3.z, acc[n][2]))));
            acc[n][3] = fmaf(a.x, w0.w, fmaf(a.y, w1.w, fmaf(a.z, w2.w, fmaf(a.w, w3.w, acc[n][3]))));
        }
    }

    float4 b  = *(const float4*)(b_self + j0);
    float4 bp = *(const float4*)(bias + j0);
    b.x += bp.x; b.y += bp.y; b.z += bp.z; b.w += bp.w;

    #pragma unroll
    for (int n = 0; n < 4; ++n) {
        int v = v0 + ns * 4 + n;
        if (v < NN) {
            float4 o;
            o.x = acc[n][0] + b.x;
            o.y = acc[n][1] + b.y;
            o.z = acc[n][2] + b.z;
            o.w = acc[n][3] + b.w;
            *(float4*)(out + (size_t)v * D + j0) = o;
        }
    }
}

extern "C" void kernel_launch(void* const* d_in, const int* in_sizes, int n_in,
                              void* d_out, int out_size, void* d_ws, size_t ws_size,
                              hipStream_t stream) {
    const float* x   = (const float*)d_in[0];
    const int*   src = (const int*)d_in[1];
    const int*   dst = (const int*)d_in[2];
    const float* ew  = (const float*)d_in[3];
    const float* Ws  = (const float*)d_in[4];
    const float* bs  = (const float*)d_in[5];
    const float* Wn  = (const float*)d_in[6];
    const float* bp  = (const float*)d_in[7];
    float* out = (float*)d_out;

    int E = in_sizes[1];
    int EPAD = E + NSCAN;                       // room for 1 pad edge per node

    // workspace layout (4B units): count and edge_sw contiguous for single memset
    int*  wsi     = (int*)d_ws;
    int*  count   = wsi;                        // NSCAN
    int2* edge_sw = (int2*)(wsi + NSCAN);       // EPAD int2 (16B-aligned: NSCAN*4 % 16 == 0)
    int*  offsets = wsi + NSCAN + 2 * EPAD;     // NSCAN
    int*  cursor  = offsets + NSCAN;            // NSCAN
    int*  bsum    = cursor + NSCAN;             // 64
    float* WT     = (float*)(bsum + 64);        // 256*128 floats
    ushort* xb    = (ushort*)(WT + 256 * 128);  // NN*D bf16

    // zero count + edge_sw (pads must read as src=0, w=0)
    hipMemsetAsync(count, 0, (size_t)(NSCAN + 2 * EPAD) * sizeof(int), stream);

    int ncvt = NN * D / 4;
    int nmax = (E > ncvt) ? E : ncvt;
    prep_kernel<<<(nmax + 255) / 256, 256, 0, stream>>>(dst, count, x, xb, Ws, Wn, WT, E);

    scan1_kernel<<<NB_SCAN, 1024, 0, stream>>>(count, offsets, bsum);
    scan23_kernel<<<NB_SCAN, 1024, 0, stream>>>(offsets, bsum, cursor);
    csr_scatter_kernel<<<(E + 255) / 256, 256, 0, stream>>>(src, dst, ew, cursor, edge_sw, E);

    fused_out_kernel<<<(NN + 31) / 32, 256, 0, stream>>>(x, xb, offsets, edge_sw,
                                                         WT, bs, bp, out);
}